// Round 4
// baseline (1886.516 us; speedup 1.0000x reference)
//
#include <hip/hip_runtime.h>
#include <math.h>

#define TS 512
#define NB 64
#define NF 64
#define NE 256
#define NH 512
#define NO 128

#define NGRP 4     // batch groups (16 rows each)
#define NSLC 16    // h-slices per group (32 h-idx each)  [R16: was 32 x 16]
#define RPG  16    // rows per group (dense MFMA A)

// ws layout (float words)
#define OFF_WCOMB 0        // 2048*64
#define OFF_BCOMB 131072   // 2048
#define OFF_HBUF  133120   // u32[2][4][512h][16b] tagged h words = 65536
#define OFF_POOL  198656   // 64*512

typedef short bf16x8 __attribute__((ext_vector_type(8)));
typedef float f32x4 __attribute__((ext_vector_type(4)));
typedef unsigned long long u64;
typedef unsigned int u32;

union F8 { bf16x8 s; unsigned short u[8]; };

__device__ __forceinline__ unsigned short f2bf(float f) {
    unsigned u = __float_as_uint(f);
    u += 0x7fffu + ((u >> 16) & 1u);
    return (unsigned short)(u >> 16);
}
__device__ __forceinline__ float bf2f(unsigned short h) {
    return __uint_as_float(((unsigned)h) << 16);
}
__device__ __forceinline__ float fast_sigmoid(float v) {
    return 1.f / (1.f + __expf(-v));
}
__device__ __forceinline__ float fast_tanh(float v) {
    return 1.f - 2.f / (1.f + __expf(2.f * v));
}
__device__ __forceinline__ u32 aload(const u32* p) {
    return __hip_atomic_load(p, __ATOMIC_RELAXED, __HIP_MEMORY_SCOPE_AGENT);
}

// W_comb[g][f] = sum_e W_ih[g][e] * W_emb[e][f];  b_comb[g] = W_ih[g]·b_emb + b_ih[g] + b_hh[g]
__global__ __launch_bounds__(256) void k_wcomb(const float* __restrict__ W_emb,
                                               const float* __restrict__ b_emb,
                                               const float* __restrict__ W_ih,
                                               const float* __restrict__ b_ih,
                                               const float* __restrict__ b_hh,
                                               float* __restrict__ W_comb,
                                               float* __restrict__ b_comb) {
    __shared__ float wih[4][NE];
    int g0 = blockIdx.x * 4;
    for (int i = threadIdx.x; i < 4 * NE; i += 256)
        wih[i >> 8][i & 255] = W_ih[(size_t)g0 * NE + i];
    __syncthreads();
    int gl = threadIdx.x >> 6, f = threadIdx.x & 63;
    float acc = 0.f;
    for (int e = 0; e < NE; ++e) acc += wih[gl][e] * W_emb[e * NF + f];
    W_comb[(size_t)(g0 + gl) * NF + f] = acc;
    if (f == 0) {
        float a2 = 0.f;
        for (int e = 0; e < NE; ++e) a2 += wih[gl][e] * b_emb[e];
        b_comb[g0 + gl] = a2 + b_ih[g0 + gl] + b_hh[g0 + gl];
    }
}

// Persistent LSTM, dense-A MFMA, REGISTER-DIRECT A-frags (R12 poll form).
// R16: second FAN-OUT halving. Poll traffic/round = NWG x 32KB (every WG
// re-reads its group slab from the coherence point each round; FETCH_SIZE
// proves it's IF$-resident). 64 WGs = 4 groups x 16 slices; each WG owns
// 32 h-channels (8 n-tiles, 128 gate cols): traffic/round 4MB -> 2MB,
// stragglers/group 32 -> 16.
// VGPR fit: (a) 3 split-precision MFMA chains SERIAL-CHAINED into one acc
// per n-tile (C-in=C-out accumulate), acc = 8 f32x4 = 32 VGPR; (b) x-work
// spread uniformly: wave w owns h k-tiles {2w,2w+1} for ALL 8 nt + x-cells
// (kt16+(w&1)) for nt {2(w>>1), 2(w>>1)+1} -> 54 MFMAs/wave, perfectly
// uniform (R15 had waves 6,7 doing +50%).
// LDS fit: part[8][64][20] (40KB, proven pad-20 layout) reused in a 2-PASS
// epilogue: write nt0-3, bar, read gates i/f, bar, write nt4-7, bar, read
// gates g/o + c/h update + publish, bar. Bias lives in registers.
// Epilogue uses ALL 512 threads (32ch x 16b pairs).
// Slab layout, tag protocol, poll loop: bit-identical to the R9-proven
// scheme. Exchange u32 {bf16hi<<16 | bf16lo&~3 | tag2}, tag2=((t+1)&3)^2.
__global__ __launch_bounds__(512, 1) void k_lstm(const float* __restrict__ x,
                                                 const float* __restrict__ W_hh,
                                                 const float* __restrict__ W_comb,
                                                 const float* __restrict__ b_comb,
                                                 u32* __restrict__ hbuf,
                                                 float* __restrict__ pooled) {
    const int wg = blockIdx.x;
    const int grp = wg & 3;            // 0..3
    const int slc = wg >> 2;           // 0..15 -> h-idx [32*slc, 32*slc+32)
    const int tid = threadIdx.x;
    const int lane = tid & 63, wave = tid >> 6;
    const int m4 = lane & 15;          // A row (batch) / B col fragment index
    const int qq = lane >> 4;          // quad
    const int kt0 = 2 * wave;          // uniform: wave w owns h k-tiles {2w,2w+1}
    const int xoff = (wave & 1) * 32 + qq * 8;  // x k-tile 16+(wave&1)
    const int ch = tid >> 4, bb = tid & 15;     // epilogue identity (32ch x 16b)

    // part single-buffered 2-pass: [wave][slot(64)][b(pad20)] = 40KB
    __shared__ __align__(16) float part[8 * 64 * 20];

    // ---- B-fragments h-side (split bf16, register-resident): 8 nt x 2 kt ----
    F8 bhi[8][2], blo[8][2];
    #pragma unroll
    for (int nt = 0; nt < 8; ++nt) {
        const int n_loc = nt * 16 + m4;                 // gate col 0..127
        const int grow = (n_loc >> 5) * NH + slc * 32 + (n_loc & 31);
        #pragma unroll
        for (int k = 0; k < 2; ++k) {
            const float* wp = W_hh + (size_t)grow * NH + (kt0 + k) * 32 + qq * 8;
            const float4 w0 = *(const float4*)wp;
            const float4 w1 = *(const float4*)(wp + 4);
            float wf[8] = {w0.x, w0.y, w0.z, w0.w, w1.x, w1.y, w1.z, w1.w};
            #pragma unroll
            for (int e = 0; e < 8; ++e) {
                unsigned short hb = f2bf(wf[e]);
                bhi[nt][k].u[e] = hb;
                blo[nt][k].u[e] = f2bf(wf[e] - bf2f(hb));
            }
        }
    }
    // ---- B-fragments x-side: 2 cells (nt = 2(wave>>1)+i, x k-tile wave&1) ----
    F8 bxhi[2], bxlo[2];
    #pragma unroll
    for (int i = 0; i < 2; ++i) {
        const int nt = (wave >> 1) * 2 + i;
        const int n_loc = nt * 16 + m4;
        const int grow = (n_loc >> 5) * NH + slc * 32 + (n_loc & 31);
        const float* wp = W_comb + (size_t)grow * NF + xoff;
        const float4 w0 = *(const float4*)wp;
        const float4 w1 = *(const float4*)(wp + 4);
        float wf[8] = {w0.x, w0.y, w0.z, w0.w, w1.x, w1.y, w1.z, w1.w};
        #pragma unroll
        for (int e = 0; e < 8; ++e) {
            unsigned short hb = f2bf(wf[e]);
            bxhi[i].u[e] = hb;
            bxlo[i].u[e] = f2bf(wf[e] - bf2f(hb));
        }
    }

    // ---- bias in registers (4 gates at this thread's channel) ----
    const float bc0 = b_comb[0 * NH + slc * 32 + ch];
    const float bc1 = b_comb[1 * NH + slc * 32 + ch];
    const float bc2 = b_comb[2 * NH + slc * 32 + ch];
    const float bc3 = b_comb[3 * NH + slc * 32 + ch];

    // ---- A-fragments in registers; t=0: h = 0; x(0) direct, prefetch x(1) ----
    F8 ahi[2], alo[2], axh, axl;
    #pragma unroll
    for (int k = 0; k < 2; ++k) {
        ahi[k].s = (bf16x8){0, 0, 0, 0, 0, 0, 0, 0};
        alo[k].s = (bf16x8){0, 0, 0, 0, 0, 0, 0, 0};
    }
    {
        const float* xr0 = x + ((size_t)(grp * RPG + m4) * TS + 0) * NF + xoff;
        const float4 a = ((const float4*)xr0)[0];
        const float4 b4 = ((const float4*)xr0)[1];
        float xf[8] = {a.x, a.y, a.z, a.w, b4.x, b4.y, b4.z, b4.w};
        #pragma unroll
        for (int e = 0; e < 8; ++e) {
            unsigned short hb = f2bf(xf[e]);
            axh.u[e] = hb;
            axl.u[e] = f2bf(xf[e] - bf2f(hb));
        }
    }
    float4 xpa, xpb;
    {
        const float* xr1 = x + ((size_t)(grp * RPG + m4) * TS + 1) * NF + xoff;
        xpa = ((const float4*)xr1)[0];
        xpb = ((const float4*)xr1)[1];
    }

    float c_reg = 0.f, hsum = 0.f;  // all 512 threads

    for (int t = 0; t < TS; ++t) {
        const bool last = (t + 1 == TS);
        const int p = t & 1;

        // ---- MFMA: serial-chained split chains into ONE acc per nt ----
        f32x4 acc[8];
        #pragma unroll
        for (int nt = 0; nt < 8; ++nt) acc[nt] = (f32x4){0.f, 0.f, 0.f, 0.f};
        #pragma unroll
        for (int nt = 0; nt < 8; ++nt) {
            #pragma unroll
            for (int k = 0; k < 2; ++k) {
                acc[nt] = __builtin_amdgcn_mfma_f32_16x16x32_bf16(ahi[k].s, bhi[nt][k].s, acc[nt], 0, 0, 0);
                acc[nt] = __builtin_amdgcn_mfma_f32_16x16x32_bf16(alo[k].s, bhi[nt][k].s, acc[nt], 0, 0, 0);
                acc[nt] = __builtin_amdgcn_mfma_f32_16x16x32_bf16(ahi[k].s, blo[nt][k].s, acc[nt], 0, 0, 0);
            }
            // x-cells: wave (w>>1) owns nt pair {2(w>>1), 2(w>>1)+1} (const idx via unroll)
            if ((nt >> 1) == (wave >> 1)) {
                const int i = nt & 1;
                acc[nt] = __builtin_amdgcn_mfma_f32_16x16x32_bf16(axh.s, bxhi[i].s, acc[nt], 0, 0, 0);
                acc[nt] = __builtin_amdgcn_mfma_f32_16x16x32_bf16(axl.s, bxhi[i].s, acc[nt], 0, 0, 0);
                acc[nt] = __builtin_amdgcn_mfma_f32_16x16x32_bf16(axh.s, bxlo[i].s, acc[nt], 0, 0, 0);
            }
        }

        // ---- pass 1: nt 0..3 (gates i,f) ----
        #pragma unroll
        for (int nt = 0; nt < 4; ++nt)
            *(f32x4*)&part[wave * 1280 + (nt * 16 + m4) * 20 + qq * 4] = acc[nt];
        __syncthreads();  // bar1: pass1 ready

        float v0 = bc0, v1 = bc1;
        #pragma unroll
        for (int w = 0; w < 8; ++w) v0 += part[w * 1280 + ch * 20 + bb];
        #pragma unroll
        for (int w = 0; w < 8; ++w) v1 += part[w * 1280 + (32 + ch) * 20 + bb];
        __syncthreads();  // bar2: pass1 reads done

        // ---- pass 2: nt 4..7 (gates g,o) ----
        #pragma unroll
        for (int nt = 4; nt < 8; ++nt)
            *(f32x4*)&part[wave * 1280 + ((nt - 4) * 16 + m4) * 20 + qq * 4] = acc[nt];
        __syncthreads();  // bar3: pass2 ready

        float v2 = bc2, v3 = bc3;
        #pragma unroll
        for (int w = 0; w < 8; ++w) v2 += part[w * 1280 + ch * 20 + bb];
        #pragma unroll
        for (int w = 0; w < 8; ++w) v3 += part[w * 1280 + (32 + ch) * 20 + bb];

        const unsigned tg2 = (unsigned)(((t + 1) & 3) ^ 2);
        u32* const slab = hbuf + ((size_t)(p * NGRP + grp)) * 8192;

        // ---- fused gate/c/h update + publish (ALL 512 threads) ----
        const float iv = fast_sigmoid(v0);
        const float fv = fast_sigmoid(v1);
        const float gv = fast_tanh(v2);
        const float ov = fast_sigmoid(v3);
        c_reg = fv * c_reg + iv * gv;
        const float h = ov * fast_tanh(c_reg);
        hsum += h;
        if (!last) {
            const unsigned short hb = f2bf(h);
            const unsigned short lb = f2bf(h - bf2f(hb));
            const u32 pk = ((u32)hb << 16) | ((u32)lb & 0xFFFCu) | tg2;
            // word = 16*hidx + batch, hidx = 32*slc + ch -> slc*512 + tid
            // (2KB contiguous per WG, full lines)
            __hip_atomic_store(&slab[slc * 512 + tid], pk,
                               __ATOMIC_RELAXED, __HIP_MEMORY_SCOPE_AGENT);
        }
        __syncthreads();  // bar4: pass2 reads done; next-iter part writes safe

        // ---- per-wave poll of own frag words + in-register assembly (R12) ----
        if (!last) {
            // lane (m4,qq) needs slab[kt*512 + qq*128 + j*16 + m4], j=0..7, kt=kt0,kt0+1
            const u32* b0 = slab + kt0 * 512 + qq * 128 + m4;
            const u32* b1 = b0 + 512;
            u32 wd[16];
            #pragma unroll
            for (int j = 0; j < 8; ++j) wd[j] = aload(b0 + j * 16);
            #pragma unroll
            for (int j = 0; j < 8; ++j) wd[8 + j] = aload(b1 + j * 16);
            int guard = 0;
            for (;;) {
                u32 bad = 0;
                #pragma unroll
                for (int i = 0; i < 16; ++i) bad |= (wd[i] & 3) ^ tg2;
                if (bad == 0) break;
                // exponential backoff: avoid poll-storm positive feedback
                if (guard < 8)       __builtin_amdgcn_s_sleep(1);
                else if (guard < 64) __builtin_amdgcn_s_sleep(4);
                else                 __builtin_amdgcn_s_sleep(16);
                #pragma unroll
                for (int j = 0; j < 8; ++j) wd[j] = aload(b0 + j * 16);
                #pragma unroll
                for (int j = 0; j < 8; ++j) wd[8 + j] = aload(b1 + j * 16);
                if (++guard > (1 << 20)) break;  // anti-hang escape
            }
            #pragma unroll
            for (int j = 0; j < 8; ++j) {
                ahi[0].u[j] = (unsigned short)(wd[j] >> 16);
                alo[0].u[j] = (unsigned short)(wd[j] & 0xFFFCu);
                ahi[1].u[j] = (unsigned short)(wd[8 + j] >> 16);
                alo[1].u[j] = (unsigned short)(wd[8 + j] & 0xFFFCu);
            }
            // x(t+1) frag from prefetch; prefetch x(t+2) — ALL waves
            {
                float xf[8] = {xpa.x, xpa.y, xpa.z, xpa.w, xpb.x, xpb.y, xpb.z, xpb.w};
                #pragma unroll
                for (int e = 0; e < 8; ++e) {
                    unsigned short hb = f2bf(xf[e]);
                    axh.u[e] = hb;
                    axl.u[e] = f2bf(xf[e] - bf2f(hb));
                }
                if (t + 2 < TS) {
                    const float* xr = x + ((size_t)(grp * RPG + m4) * TS + (t + 2)) * NF + xoff;
                    xpa = ((const float4*)xr)[0];
                    xpb = ((const float4*)xr)[1];
                }
            }
        }
        // no trailing barrier: A-frags are wave-private registers
    }

    pooled[(size_t)(grp * RPG + bb) * NH + slc * 32 + ch] = hsum * (1.f / TS);
}

// out[b][o] = pooled[b]·W_fc[o] + b_fc[o]
__global__ __launch_bounds__(256) void k_fc(const float* __restrict__ pooled,
                                            const float* __restrict__ W_fc,
                                            const float* __restrict__ b_fc,
                                            float* __restrict__ out) {
    __shared__ float pl[2][NH];
    const int b0 = blockIdx.x * 2;
    for (int i = threadIdx.x; i < 2 * NH; i += 256)
        pl[i >> 9][i & 511] = pooled[(size_t)b0 * NH + i];
    __syncthreads();
    const int o = threadIdx.x & 127, bl = threadIdx.x >> 7;
    const float* wr = W_fc + (size_t)o * NH;
    float acc = 0.f;
    #pragma unroll 4
    for (int k = 0; k < NH; k += 4) {
        const float4 wv = *(const float4*)&wr[k];
        acc += pl[bl][k] * wv.x + pl[bl][k + 1] * wv.y +
               pl[bl][k + 2] * wv.z + pl[bl][k + 3] * wv.w;
    }
    out[(size_t)(b0 + bl) * NO + o] = acc + b_fc[o];
}

extern "C" void kernel_launch(void* const* d_in, const int* in_sizes, int n_in,
                              void* d_out, int out_size, void* d_ws, size_t ws_size,
                              hipStream_t stream) {
    const float* x     = (const float*)d_in[0];
    const float* W_emb = (const float*)d_in[1];
    const float* b_emb = (const float*)d_in[2];
    const float* W_ih  = (const float*)d_in[3];
    const float* W_hh  = (const float*)d_in[4];
    const float* b_ih  = (const float*)d_in[5];
    const float* b_hh  = (const float*)d_in[6];
    const float* W_fc  = (const float*)d_in[7];
    const float* b_fc  = (const float*)d_in[8];
    float* out = (float*)d_out;
    float* ws  = (float*)d_ws;

    float* W_comb = ws + OFF_WCOMB;
    float* b_comb = ws + OFF_BCOMB;
    u32*   hbuf   = (u32*)(ws + OFF_HBUF);
    float* pooled = ws + OFF_POOL;

    hipLaunchKernelGGL(k_wcomb, dim3(512), dim3(256), 0, stream,
                       W_emb, b_emb, W_ih, b_ih, b_hh, W_comb, b_comb);
    hipLaunchKernelGGL(k_lstm,  dim3(64),  dim3(512), 0, stream,
                       x, W_hh, W_comb, b_comb, hbuf, pooled);
    hipLaunchKernelGGL(k_fc,    dim3(32),  dim3(256), 0, stream,
                       pooled, W_fc, b_fc, out);
}

// Round 5
// 1447.786 us; speedup vs baseline: 1.3030x; 1.3030x over previous
//
#include <hip/hip_runtime.h>
#include <math.h>

#define TS 512
#define NB 64
#define NF 64
#define NE 256
#define NH 512
#define NO 128

#define NGRP 4     // batch groups (16 rows each)
#define NSLC 32    // h-slices per group (16 h-idx each)  [R15 structure]
#define RPG  16    // rows per group (dense MFMA A)

// ws layout (float words)
#define OFF_WCOMB 0        // 2048*64
#define OFF_BCOMB 131072   // 2048
#define OFF_HBUF  133120   // u32[2][4][512h][16b] tagged h words = 65536
#define OFF_POOL  198656   // 64*512

typedef short bf16x8 __attribute__((ext_vector_type(8)));
typedef float f32x4 __attribute__((ext_vector_type(4)));
typedef unsigned long long u64;
typedef unsigned int u32;

union F8 { bf16x8 s; unsigned short u[8]; };

__device__ __forceinline__ unsigned short f2bf(float f) {
    unsigned u = __float_as_uint(f);
    u += 0x7fffu + ((u >> 16) & 1u);
    return (unsigned short)(u >> 16);
}
__device__ __forceinline__ float bf2f(unsigned short h) {
    return __uint_as_float(((unsigned)h) << 16);
}
__device__ __forceinline__ float fast_sigmoid(float v) {
    return 1.f / (1.f + __expf(-v));
}
__device__ __forceinline__ float fast_tanh(float v) {
    return 1.f - 2.f / (1.f + __expf(2.f * v));
}
__device__ __forceinline__ u32 aload(const u32* p) {
    return __hip_atomic_load(p, __ATOMIC_RELAXED, __HIP_MEMORY_SCOPE_AGENT);
}

// W_comb[g][f] = sum_e W_ih[g][e] * W_emb[e][f];  b_comb[g] = W_ih[g]·b_emb + b_ih[g] + b_hh[g]
__global__ __launch_bounds__(256) void k_wcomb(const float* __restrict__ W_emb,
                                               const float* __restrict__ b_emb,
                                               const float* __restrict__ W_ih,
                                               const float* __restrict__ b_ih,
                                               const float* __restrict__ b_hh,
                                               float* __restrict__ W_comb,
                                               float* __restrict__ b_comb) {
    __shared__ float wih[4][NE];
    int g0 = blockIdx.x * 4;
    for (int i = threadIdx.x; i < 4 * NE; i += 256)
        wih[i >> 8][i & 255] = W_ih[(size_t)g0 * NE + i];
    __syncthreads();
    int gl = threadIdx.x >> 6, f = threadIdx.x & 63;
    float acc = 0.f;
    for (int e = 0; e < NE; ++e) acc += wih[gl][e] * W_emb[e * NF + f];
    W_comb[(size_t)(g0 + gl) * NF + f] = acc;
    if (f == 0) {
        float a2 = 0.f;
        for (int e = 0; e < NE; ++e) a2 += wih[gl][e] * b_emb[e];
        b_comb[g0 + gl] = a2 + b_ih[g0 + gl] + b_hh[g0 + gl];
    }
}

// Persistent LSTM, dense-A MFMA, REGISTER-DIRECT A-frags (R12 poll form).
// R15 structure (best: 1340us): 128 WGs = 4 batch-groups x 32 gate-slices;
// each WG owns 16 h-channels (4 n-tiles); part[] single-buffered (40KB,
// pad-20), 2 barriers/step; slab/tag/poll protocol R9-proven.
// R17 (this round): critical-path shaving, NO structural changes.
//  (1) UNIFORM WAVES: 16 h k-tiles + 8 x-cells (4nt x 2xkt) over 8 waves ->
//      wave w owns h k-tiles {2w,2w+1} for all 4 nt (24 MFMAs) + ONE x-cell
//      (nt=w&3, xkt=w>>2; 3 MFMAs) = 27 MFMAs each. R15 had waves 6,7 at 36
//      (+50%) — every step's bar1 AND every consumer's poll waited on them.
//      x A-frag redundancy (waves sharing xkt load same rows) is L2-cached.
//  (2) POST-DETECT TRIM: x(t+1) fragment conversion + x(t+2) prefetch issue
//      moved BEFORE the poll loop (depends only on prefetched regs) — ~60
//      VALU ops removed from the detect->MFMA critical path.
//  (3) Backoff cap sleep(16)->sleep(8): halves worst-case overshoot quantum.
// Exchange u32 {bf16hi<<16 | bf16lo&~3 | tag2}, tag2=((t+1)&3)^2.
__global__ __launch_bounds__(512, 1) void k_lstm(const float* __restrict__ x,
                                                 const float* __restrict__ W_hh,
                                                 const float* __restrict__ W_comb,
                                                 const float* __restrict__ b_comb,
                                                 u32* __restrict__ hbuf,
                                                 float* __restrict__ pooled) {
    const int wg = blockIdx.x;
    const int grp = wg & 3;            // 0..3
    const int slc = wg >> 2;           // 0..31 -> h-idx [16*slc, 16*slc+16)
    const int tid = threadIdx.x;
    const int lane = tid & 63, wave = tid >> 6;
    const int m4 = lane & 15;          // A row (batch) / B col fragment index
    const int qq = lane >> 4;          // quad
    const int kt0 = 2 * wave;          // uniform: wave w owns h k-tiles {2w,2w+1}
    const int nt_x = wave & 3;         // owned x-cell: n-tile
    const int xoff = (wave >> 2) * 32 + qq * 8;  // owned x-cell: k-cols

    // part single-buffered: [wave][n_loc(64)][b(pad20)] = 40KB
    __shared__ __align__(16) float part[8 * 64 * 20];
    __shared__ float bcl[64];

    // ---- B-fragments h-side (split bf16, register-resident): 4 nt x 2 kt ----
    F8 bhi[4][2], blo[4][2];
    #pragma unroll
    for (int nt = 0; nt < 4; ++nt) {
        // n_loc = nt*16 + m4; gate type = nt, h-channel = m4
        const int grow = nt * NH + slc * 16 + m4;
        #pragma unroll
        for (int k = 0; k < 2; ++k) {
            const float* wp = W_hh + (size_t)grow * NH + (kt0 + k) * 32 + qq * 8;
            const float4 w0 = *(const float4*)wp;
            const float4 w1 = *(const float4*)(wp + 4);
            float wf[8] = {w0.x, w0.y, w0.z, w0.w, w1.x, w1.y, w1.z, w1.w};
            #pragma unroll
            for (int e = 0; e < 8; ++e) {
                unsigned short hb = f2bf(wf[e]);
                bhi[nt][k].u[e] = hb;
                blo[nt][k].u[e] = f2bf(wf[e] - bf2f(hb));
            }
        }
    }
    // ---- B-fragment x-side: ONE cell (nt = wave&3, x k-cols xoff) ----
    F8 bxhi, bxlo;
    {
        const int grow = nt_x * NH + slc * 16 + m4;
        const float* wp = W_comb + (size_t)grow * NF + xoff;
        const float4 w0 = *(const float4*)wp;
        const float4 w1 = *(const float4*)(wp + 4);
        float wf[8] = {w0.x, w0.y, w0.z, w0.w, w1.x, w1.y, w1.z, w1.w};
        #pragma unroll
        for (int e = 0; e < 8; ++e) {
            unsigned short hb = f2bf(wf[e]);
            bxhi.u[e] = hb;
            bxlo.u[e] = f2bf(wf[e] - bf2f(hb));
        }
    }

    if (tid < 64) bcl[tid] = b_comb[(tid >> 4) * NH + slc * 16 + (tid & 15)];

    // ---- A-fragments in registers; t=0: h = 0; x(0) direct, prefetch x(1) ----
    F8 ahi[2], alo[2], axh, axl;
    #pragma unroll
    for (int k = 0; k < 2; ++k) {
        ahi[k].s = (bf16x8){0, 0, 0, 0, 0, 0, 0, 0};
        alo[k].s = (bf16x8){0, 0, 0, 0, 0, 0, 0, 0};
    }
    {
        const float* xr0 = x + ((size_t)(grp * RPG + m4) * TS + 0) * NF + xoff;
        const float4 a = ((const float4*)xr0)[0];
        const float4 b4 = ((const float4*)xr0)[1];
        float xf[8] = {a.x, a.y, a.z, a.w, b4.x, b4.y, b4.z, b4.w};
        #pragma unroll
        for (int e = 0; e < 8; ++e) {
            unsigned short hb = f2bf(xf[e]);
            axh.u[e] = hb;
            axl.u[e] = f2bf(xf[e] - bf2f(hb));
        }
    }
    float4 xpa, xpb;
    {
        const float* xr1 = x + ((size_t)(grp * RPG + m4) * TS + 1) * NF + xoff;
        xpa = ((const float4*)xr1)[0];
        xpb = ((const float4*)xr1)[1];
    }

    float c_reg = 0.f, hsum = 0.f;  // live on tid<256
    __syncthreads();  // bcl ready

    for (int t = 0; t < TS; ++t) {
        const bool last = (t + 1 == TS);
        const int p = t & 1;

        // ---- MFMA: 4 nt x 3 split chains x 2 h k-tiles + owned x-cell ----
        f32x4 acc[4][3];
        #pragma unroll
        for (int nt = 0; nt < 4; ++nt)
            #pragma unroll
            for (int c = 0; c < 3; ++c) acc[nt][c] = (f32x4){0.f, 0.f, 0.f, 0.f};
        #pragma unroll
        for (int k = 0; k < 2; ++k) {
            const bf16x8 ah = ahi[k].s;
            const bf16x8 al = alo[k].s;
            #pragma unroll
            for (int nt = 0; nt < 4; ++nt) {
                acc[nt][0] = __builtin_amdgcn_mfma_f32_16x16x32_bf16(ah, bhi[nt][k].s, acc[nt][0], 0, 0, 0);
                acc[nt][1] = __builtin_amdgcn_mfma_f32_16x16x32_bf16(al, bhi[nt][k].s, acc[nt][1], 0, 0, 0);
                acc[nt][2] = __builtin_amdgcn_mfma_f32_16x16x32_bf16(ah, blo[nt][k].s, acc[nt][2], 0, 0, 0);
            }
        }
        #pragma unroll
        for (int nt = 0; nt < 4; ++nt) {
            if (nt == nt_x) {  // wave-uniform branch
                acc[nt][0] = __builtin_amdgcn_mfma_f32_16x16x32_bf16(axh.s, bxhi.s, acc[nt][0], 0, 0, 0);
                acc[nt][1] = __builtin_amdgcn_mfma_f32_16x16x32_bf16(axl.s, bxhi.s, acc[nt][1], 0, 0, 0);
                acc[nt][2] = __builtin_amdgcn_mfma_f32_16x16x32_bf16(axh.s, bxlo.s, acc[nt][2], 0, 0, 0);
            }
        }
        #pragma unroll
        for (int nt = 0; nt < 4; ++nt) {
            const f32x4 a = acc[nt][0] + acc[nt][1] + acc[nt][2];
            *(float4*)&part[wave * 1280 + (nt * 16 + m4) * 20 + qq * 4] =
                make_float4(a.x, a.y, a.z, a.w);
        }
        __syncthreads();  // bar1: part ready

        const unsigned tg2 = (unsigned)(((t + 1) & 3) ^ 2);
        u32* const slab = hbuf + ((size_t)(p * NGRP + grp)) * 8192;

        // ---- fused epilogue + publish (waves 0-3): j = tid>>4 (channel), b = tid&15 ----
        if (tid < 256) {
            const int j = tid >> 4, b = tid & 15;
            float v[4];
            #pragma unroll
            for (int ty = 0; ty < 4; ++ty) {
                const int n_loc = ty * 16 + j;
                float s = bcl[n_loc];
                #pragma unroll
                for (int w = 0; w < 8; ++w) s += part[w * 1280 + n_loc * 20 + b];
                v[ty] = s;
            }
            const float iv = fast_sigmoid(v[0]);
            const float fv = fast_sigmoid(v[1]);
            const float gv = fast_tanh(v[2]);
            const float ov = fast_sigmoid(v[3]);
            c_reg = fv * c_reg + iv * gv;
            const float h = ov * fast_tanh(c_reg);
            hsum += h;
            if (!last) {
                const unsigned short hb = f2bf(h);
                const unsigned short lb = f2bf(h - bf2f(hb));
                const u32 pk = ((u32)hb << 16) | ((u32)lb & 0xFFFCu) | tg2;
                // word = 16*hidx + batch, hidx = 16*slc + j -> slc*256 + tid
                // (1KB contiguous per WG, full lines)
                __hip_atomic_store(&slab[slc * 256 + tid], pk,
                                   __ATOMIC_RELAXED, __HIP_MEMORY_SCOPE_AGENT);
            }
        }
        __syncthreads();  // bar2: part consumed; next-iter writes safe

        if (!last) {
            // ---- x(t+1) frag conversion FIRST (independent of poll), then
            //      issue x(t+2) prefetch — off the detect->MFMA path ----
            {
                float xf[8] = {xpa.x, xpa.y, xpa.z, xpa.w, xpb.x, xpb.y, xpb.z, xpb.w};
                #pragma unroll
                for (int e = 0; e < 8; ++e) {
                    unsigned short hb = f2bf(xf[e]);
                    axh.u[e] = hb;
                    axl.u[e] = f2bf(xf[e] - bf2f(hb));
                }
                if (t + 2 < TS) {
                    const float* xr = x + ((size_t)(grp * RPG + m4) * TS + (t + 2)) * NF + xoff;
                    xpa = ((const float4*)xr)[0];
                    xpb = ((const float4*)xr)[1];
                }
            }
            // ---- per-wave poll of own frag words + in-register assembly ----
            // lane (m4,qq) needs slab[kt*512 + qq*128 + j*16 + m4], j=0..7, kt=kt0,kt0+1
            const u32* b0 = slab + kt0 * 512 + qq * 128 + m4;
            const u32* b1 = b0 + 512;
            u32 wd[16];
            #pragma unroll
            for (int j = 0; j < 8; ++j) wd[j] = aload(b0 + j * 16);
            #pragma unroll
            for (int j = 0; j < 8; ++j) wd[8 + j] = aload(b1 + j * 16);
            int guard = 0;
            for (;;) {
                u32 bad = 0;
                #pragma unroll
                for (int i = 0; i < 16; ++i) bad |= (wd[i] & 3) ^ tg2;
                if (bad == 0) break;
                // backoff: bounded overshoot (cap 8 = 512cy quantum)
                if (guard < 8)       __builtin_amdgcn_s_sleep(1);
                else if (guard < 64) __builtin_amdgcn_s_sleep(2);
                else                 __builtin_amdgcn_s_sleep(8);
                #pragma unroll
                for (int j = 0; j < 8; ++j) wd[j] = aload(b0 + j * 16);
                #pragma unroll
                for (int j = 0; j < 8; ++j) wd[8 + j] = aload(b1 + j * 16);
                if (++guard > (1 << 20)) break;  // anti-hang escape
            }
            #pragma unroll
            for (int j = 0; j < 8; ++j) {
                ahi[0].u[j] = (unsigned short)(wd[j] >> 16);
                alo[0].u[j] = (unsigned short)(wd[j] & 0xFFFCu);
                ahi[1].u[j] = (unsigned short)(wd[8 + j] >> 16);
                alo[1].u[j] = (unsigned short)(wd[8 + j] & 0xFFFCu);
            }
        }
        // no trailing barrier: A-frags are wave-private registers
    }

    if (tid < 256) {
        const int j = tid >> 4, b = tid & 15;
        pooled[(size_t)(grp * RPG + b) * NH + slc * 16 + j] = hsum * (1.f / TS);
    }
}

// out[b][o] = pooled[b]·W_fc[o] + b_fc[o]
__global__ __launch_bounds__(256) void k_fc(const float* __restrict__ pooled,
                                            const float* __restrict__ W_fc,
                                            const float* __restrict__ b_fc,
                                            float* __restrict__ out) {
    __shared__ float pl[2][NH];
    const int b0 = blockIdx.x * 2;
    for (int i = threadIdx.x; i < 2 * NH; i += 256)
        pl[i >> 9][i & 511] = pooled[(size_t)b0 * NH + i];
    __syncthreads();
    const int o = threadIdx.x & 127, bl = threadIdx.x >> 7;
    const float* wr = W_fc + (size_t)o * NH;
    float acc = 0.f;
    #pragma unroll 4
    for (int k = 0; k < NH; k += 4) {
        const float4 wv = *(const float4*)&wr[k];
        acc += pl[bl][k] * wv.x + pl[bl][k + 1] * wv.y +
               pl[bl][k + 2] * wv.z + pl[bl][k + 3] * wv.w;
    }
    out[(size_t)(b0 + bl) * NO + o] = acc + b_fc[o];
}

extern "C" void kernel_launch(void* const* d_in, const int* in_sizes, int n_in,
                              void* d_out, int out_size, void* d_ws, size_t ws_size,
                              hipStream_t stream) {
    const float* x     = (const float*)d_in[0];
    const float* W_emb = (const float*)d_in[1];
    const float* b_emb = (const float*)d_in[2];
    const float* W_ih  = (const float*)d_in[3];
    const float* W_hh  = (const float*)d_in[4];
    const float* b_ih  = (const float*)d_in[5];
    const float* b_hh  = (const float*)d_in[6];
    const float* W_fc  = (const float*)d_in[7];
    const float* b_fc  = (const float*)d_in[8];
    float* out = (float*)d_out;
    float* ws  = (float*)d_ws;

    float* W_comb = ws + OFF_WCOMB;
    float* b_comb = ws + OFF_BCOMB;
    u32*   hbuf   = (u32*)(ws + OFF_HBUF);
    float* pooled = ws + OFF_POOL;

    hipLaunchKernelGGL(k_wcomb, dim3(512), dim3(256), 0, stream,
                       W_emb, b_emb, W_ih, b_ih, b_hh, W_comb, b_comb);
    hipLaunchKernelGGL(k_lstm,  dim3(128), dim3(512), 0, stream,
                       x, W_hh, W_comb, b_comb, hbuf, pooled);
    hipLaunchKernelGGL(k_fc,    dim3(32),  dim3(256), 0, stream,
                       pooled, W_fc, b_fc, out);
}